// Round 7
// baseline (319.581 us; speedup 1.0000x reference)
//
#include <hip/hip_runtime.h>

typedef __attribute__((ext_vector_type(8))) short short8;
typedef __attribute__((ext_vector_type(4))) float f32x4;
typedef unsigned short u16;
typedef unsigned int u32;

#define BM 256
#define BN 256
#define BK 32
#define NBUF 4
#define LDP 40   // fused-fallback padded stride

__device__ __forceinline__ u16 f2bf_rne(float f) {
    u32 u = __float_as_uint(f);
    return (u16)((u + 0x7fffu + ((u >> 16) & 1u)) >> 16);
}
__device__ __forceinline__ float bf2f(u16 b) { return __uint_as_float(((u32)b) << 16); }

// ---------------- prep kernels (unchanged, proven) ----------------

__global__ __launch_bounds__(256)
void prep_w(const int* __restrict__ WP, const float* __restrict__ S,
            const float* __restrict__ Z, u16* __restrict__ Wd, int NG)
{
    const int tid = blockIdx.x * blockDim.x + threadIdx.x;
    const int o = tid / NG, g = tid % NG;
    const float s = S[o * NG + g];
    const float nzs = -Z[o * NG + g] * s;
    const int4* p = (const int4*)&WP[(size_t)(o * NG + g) * 16];
    __align__(16) u16 out[32];
    #pragma unroll
    for (int q4 = 0; q4 < 4; ++q4) {
        const int4 v4 = p[q4];
        const int vv[4] = {v4.x, v4.y, v4.z, v4.w};
        #pragma unroll
        for (int j = 0; j < 4; ++j) {
            const int v = vv[j];
            out[(q4 * 4 + j) * 2]     = f2bf_rne(fmaf((float)(v & 15), s, nzs));
            out[(q4 * 4 + j) * 2 + 1] = f2bf_rne(fmaf((float)((v >> 4) & 15), s, nzs));
        }
    }
    uint4* dst = (uint4*)&Wd[(size_t)tid * 32];
    const uint4* src = (const uint4*)out;
    dst[0] = src[0]; dst[1] = src[1]; dst[2] = src[2]; dst[3] = src[3];
}

__global__ __launch_bounds__(256)
void prep_x(const float* __restrict__ X, u16* __restrict__ Xh)
{
    const int tid = blockIdx.x * blockDim.x + threadIdx.x;
    const float4 v0 = ((const float4*)X)[tid * 2];
    const float4 v1 = ((const float4*)X)[tid * 2 + 1];
    const float f[8] = {v0.x, v0.y, v0.z, v0.w, v1.x, v1.y, v1.z, v1.w};
    __align__(16) u16 h[8];
    #pragma unroll
    for (int j = 0; j < 8; ++j) h[j] = f2bf_rne(f[j]);
    ((uint4*)Xh)[tid] = *(uint4*)h;
}

// ------- deep-pipelined 256x256 GEMM: C = Xh·Wd^T + bias -------
// 512 thr (8 waves: 2m x 4n), BK=32, 4-deep LDS ring, counted vmcnt(8),
// NEXT-TILE ds_read prefetch overlapped with current MFMA cluster.

#define GLDS(gptr, ldsbase)                                                         \
    __builtin_amdgcn_global_load_lds(                                               \
        (const __attribute__((address_space(1))) u32*)(gptr),                       \
        (__attribute__((address_space(3))) u32*)(ldsbase), 16, 0, 0)

__global__ __launch_bounds__(512, 2)
void gemm_q4(const u16* __restrict__ Xh, const u16* __restrict__ Wd,
             const float* __restrict__ Bi, float* __restrict__ C,
             int M, int N, int K)
{
    // 4 ring buffers x 16KB per operand = 128 KiB total
    __shared__ __align__(16) u16 sA[NBUF * 8192];
    __shared__ __align__(16) u16 sB[NBUF * 8192];

    const int nbx = N / BN;                  // 16
    const int nwg = gridDim.x;               // 256 (%8==0 -> simple bijective)
    const int cpx = nwg >> 3;
    const int bid = blockIdx.x;
    const int swz = (bid & 7) * cpx + (bid >> 3);
    const int bx = swz % nbx, by = swz / nbx;
    const int brow = by * BM, bcol = bx * BN;

    const int t = threadIdx.x;
    const int lane = t & 63;
    const int wid = t >> 6;                  // 0..7
    const int wr = wid >> 2;                 // 0..1  (128-row block)
    const int wcn = wid & 3;                 // 0..3  (64-col block)
    const int fr = lane & 15;
    const int ps8 = (((lane >> 4) ^ ((lane >> 2) & 3)) << 3);

    // staging geometry (as round 6; write-side involution matches read-side)
    const int srow = wid * 16 + (lane >> 2);
    const int schunk = ((lane & 3) ^ ((lane >> 4) & 3)) * 8;
    const u16* srcA0 = Xh + (size_t)(brow + srow) * K + schunk;
    const u16* srcA1 = Xh + (size_t)(brow + 128 + srow) * K + schunk;
    const u16* srcB0 = Wd + (size_t)(bcol + srow) * K + schunk;
    const u16* srcB1 = Wd + (size_t)(bcol + 128 + srow) * K + schunk;

    f32x4 acc[8][4];
    #pragma unroll
    for (int m = 0; m < 8; ++m)
        #pragma unroll
        for (int n = 0; n < 4; ++n) acc[m][n] = (f32x4)0.f;

    const int nkt = K / BK;                  // 128

#define STAGE(bufi, kt)                                                   \
    do {                                                                  \
        const size_t ko = (size_t)(kt) * BK;                              \
        char* baA = (char*)sA + (bufi) * 16384 + wid * 1024;              \
        char* baB = (char*)sB + (bufi) * 16384 + wid * 1024;              \
        GLDS(srcA0 + ko, baA);                                            \
        GLDS(srcA1 + ko, baA + 8192);                                     \
        GLDS(srcB0 + ko, baB);                                            \
        GLDS(srcB1 + ko, baB + 8192);                                     \
    } while (0)

#define READ_FRAGS(dst_a, dst_b, bufi)                                    \
    do {                                                                  \
        const u16* _bA = sA + (bufi) * 8192;                              \
        const u16* _bB = sB + (bufi) * 8192;                              \
        _Pragma("unroll")                                                 \
        for (int m = 0; m < 8; ++m) {                                     \
            const int row = wr * 128 + m * 16 + fr;                       \
            dst_a[m] = *(const short8*)&_bA[row * 32 + ps8];              \
        }                                                                 \
        _Pragma("unroll")                                                 \
        for (int n = 0; n < 4; ++n) {                                     \
            const int row = wcn * 64 + n * 16 + fr;                       \
            dst_b[n] = *(const short8*)&_bB[row * 32 + ps8];              \
        }                                                                 \
    } while (0)

    // ---- prologue: fill the 4-deep ring; tiles 0,1 landed before loop ----
    STAGE(0, 0);
    STAGE(1, 1);
    STAGE(2, 2);
    STAGE(3, 3);
    asm volatile("s_waitcnt vmcnt(8)" ::: "memory");   // tiles 0,1 landed
    __builtin_amdgcn_s_barrier();

    short8 a[8], b[4];
    READ_FRAGS(a, b, 0);                                // fragments of tile 0

    for (int kt = 0; kt < nkt; ++kt) {
        const int cur = kt & 3;
        const int nxt = (kt + 1) & 3;

        // ---- prefetch next tile's fragments (tile kt+1 is landed) ----
        short8 na[8], nb[4];
        if (kt + 1 < nkt) READ_FRAGS(na, nb, nxt);

        // ---- MFMA on current regs, overlapping the in-flight ds_reads ----
        __builtin_amdgcn_s_setprio(1);
        #pragma unroll
        for (int m = 0; m < 8; ++m)
            #pragma unroll
            for (int n = 0; n < 4; ++n)
                acc[m][n] = __builtin_amdgcn_mfma_f32_16x16x32_bf16(a[m], b[n], acc[m][n], 0, 0, 0);
        __builtin_amdgcn_s_setprio(0);
        __builtin_amdgcn_sched_barrier(0);   // pin reads+MFMA above the drain

        // all waves' LDS reads retired -> safe to restage oldest buffer
        asm volatile("s_waitcnt lgkmcnt(0)" ::: "memory");
        __builtin_amdgcn_s_barrier();

        if (kt + 4 < nkt) STAGE(cur, kt + 4);

        if (kt + 1 < nkt) {
            #pragma unroll
            for (int m = 0; m < 8; ++m) a[m] = na[m];
            #pragma unroll
            for (int n = 0; n < 4; ++n) b[n] = nb[n];
        }

        // counted vmcnt: require tiles <= kt+2 landed (2 tiles / 8 loads in flight)
        if (kt + 4 < nkt)      asm volatile("s_waitcnt vmcnt(8)" ::: "memory");
        else if (kt + 3 < nkt) asm volatile("s_waitcnt vmcnt(4)" ::: "memory");
        else                   asm volatile("s_waitcnt vmcnt(0)" ::: "memory");
        __builtin_amdgcn_s_barrier();
    }

    // ---- epilogue: C = acc + bias (layout: col=lane&15, row=(lane>>4)*4+i) ----
    const int row4 = (lane >> 4) << 2;
    const int col = lane & 15;
    #pragma unroll
    for (int n = 0; n < 4; ++n) {
        const int gc = bcol + wcn * 64 + n * 16 + col;
        const float bb = Bi[gc];
        #pragma unroll
        for (int m = 0; m < 8; ++m) {
            const int gr = brow + wr * 128 + m * 16 + row4;
            #pragma unroll
            for (int i = 0; i < 4; ++i)
                C[(size_t)(gr + i) * N + gc] = acc[m][n][i] + bb;
        }
    }
}
#undef READ_FRAGS
#undef STAGE
#undef GLDS

// ---------------- fused fallback (round-1 kernel, proven) ----------------

__global__ __launch_bounds__(256, 2)
void q4_gemm_fused(const float* __restrict__ X, const int* __restrict__ WP,
                   const float* __restrict__ S, const float* __restrict__ Z,
                   const float* __restrict__ Bi, float* __restrict__ C,
                   int M, int N, int K, int NG)
{
    __shared__ __align__(16) u16 sa_hi[128][LDP];
    __shared__ __align__(16) u16 sa_lo[128][LDP];
    __shared__ __align__(16) u16 sb_hi[128][LDP];
    __shared__ __align__(16) u16 sb_lo[128][LDP];

    const int nbx = N / 128;
    const int bx = blockIdx.x % nbx;
    const int by = blockIdx.x / nbx;
    const int brow = by * 128, bcol = bx * 128;

    const int t = threadIdx.x;
    const int lane = t & 63;
    const int wid = t >> 6;
    const int wr = wid >> 1, wc = wid & 1;
    const int xc4 = t & 7, xr0 = t >> 3;
    const int wrow = t >> 1, whalf = t & 1;
    const int Kh = K >> 1;

    f32x4 acc[4][4];
    #pragma unroll
    for (int m = 0; m < 4; ++m)
        #pragma unroll
        for (int n = 0; n < 4; ++n) acc[m][n] = (f32x4)0.f;

    const int fr = lane & 15;
    const int k8 = (lane >> 4) << 3;

    const int nkt = K / 32;
    for (int kt = 0; kt < nkt; ++kt) {
        #pragma unroll
        for (int p = 0; p < 4; ++p) {
            const int r = xr0 + p * 32;
            const float4 v = *(const float4*)&X[(size_t)(brow + r) * K + kt * 32 + xc4 * 4];
            u16 h[4], l[4];
            const float f[4] = {v.x, v.y, v.z, v.w};
            #pragma unroll
            for (int j = 0; j < 4; ++j) {
                h[j] = f2bf_rne(f[j]);
                l[j] = f2bf_rne(f[j] - bf2f(h[j]));
            }
            *(ushort4*)&sa_hi[r][xc4 * 4] = *(ushort4*)h;
            *(ushort4*)&sa_lo[r][xc4 * 4] = *(ushort4*)l;
        }
        {
            const int n = bcol + wrow;
            const float s = S[n * NG + kt];
            const float z = Z[n * NG + kt];
            const float nzs = -z * s;
            const int4* pp = (const int4*)&WP[(size_t)n * Kh + kt * 16 + whalf * 8];
            const int4 p0 = pp[0], p1 = pp[1];
            const int vals[8] = {p0.x, p0.y, p0.z, p0.w, p1.x, p1.y, p1.z, p1.w};
            __align__(16) u16 hi[16], lo[16];
            #pragma unroll
            for (int j = 0; j < 8; ++j) {
                const int v = vals[j];
                const float w0 = fmaf((float)(v & 15), s, nzs);
                const float w1 = fmaf((float)((v >> 4) & 15), s, nzs);
                hi[2 * j] = f2bf_rne(w0); lo[2 * j] = f2bf_rne(w0 - bf2f(hi[2 * j]));
                hi[2 * j + 1] = f2bf_rne(w1); lo[2 * j + 1] = f2bf_rne(w1 - bf2f(hi[2 * j + 1]));
            }
            #pragma unroll
            for (int q = 0; q < 4; ++q) {
                *(ushort4*)&sb_hi[wrow][whalf * 16 + q * 4] = *(ushort4*)&hi[q * 4];
                *(ushort4*)&sb_lo[wrow][whalf * 16 + q * 4] = *(ushort4*)&lo[q * 4];
            }
        }
        __syncthreads();

        short8 ah[4], al[4], bh[4], bl[4];
        #pragma unroll
        for (int m = 0; m < 4; ++m) {
            ah[m] = *(const short8*)&sa_hi[wr * 64 + m * 16 + fr][k8];
            al[m] = *(const short8*)&sa_lo[wr * 64 + m * 16 + fr][k8];
        }
        #pragma unroll
        for (int n = 0; n < 4; ++n) {
            bh[n] = *(const short8*)&sb_hi[wc * 64 + n * 16 + fr][k8];
            bl[n] = *(const short8*)&sb_lo[wc * 64 + n * 16 + fr][k8];
        }
        #pragma unroll
        for (int m = 0; m < 4; ++m)
            #pragma unroll
            for (int n = 0; n < 4; ++n) {
                acc[m][n] = __builtin_amdgcn_mfma_f32_16x16x32_bf16(ah[m], bh[n], acc[m][n], 0, 0, 0);
                acc[m][n] = __builtin_amdgcn_mfma_f32_16x16x32_bf16(ah[m], bl[n], acc[m][n], 0, 0, 0);
                acc[m][n] = __builtin_amdgcn_mfma_f32_16x16x32_bf16(al[m], bh[n], acc[m][n], 0, 0, 0);
            }
        __syncthreads();
    }

    const int row4 = (lane >> 4) << 2;
    const int col = lane & 15;
    #pragma unroll
    for (int n = 0; n < 4; ++n) {
        const int gc = bcol + wc * 64 + n * 16 + col;
        const float bb = Bi[gc];
        #pragma unroll
        for (int m = 0; m < 4; ++m) {
            const int gr = brow + wr * 64 + m * 16 + row4;
            #pragma unroll
            for (int i = 0; i < 4; ++i)
                C[(size_t)(gr + i) * N + gc] = acc[m][n][i] + bb;
        }
    }
}

// ---------------- launch ----------------

extern "C" void kernel_launch(void* const* d_in, const int* in_sizes, int n_in,
                              void* d_out, int out_size, void* d_ws, size_t ws_size,
                              hipStream_t stream)
{
    const float* X  = (const float*)d_in[0];
    const int*   WP = (const int*)d_in[1];
    const float* S  = (const float*)d_in[2];
    const float* Z  = (const float*)d_in[3];
    const float* Bi = (const float*)d_in[4];
    float* C = (float*)d_out;

    const int O  = in_sizes[4];            // 4096
    const int NG = in_sizes[2] / O;        // 128
    const int K  = NG * 32;                // 4096
    const int M  = in_sizes[0] / K;        // 4096

    const size_t needW = (size_t)O * K * 2;
    const size_t needX = (size_t)M * K * 2;
    const size_t need = needW + needX;

    if (ws_size >= need && (M % BM) == 0 && (O % BN) == 0) {
        u16* Wd  = (u16*)d_ws;
        u16* Xhp = Wd + (size_t)O * K;

        prep_w<<<(O * NG) / 256, 256, 0, stream>>>(WP, S, Z, Wd, NG);
        prep_x<<<(M * K / 8) / 256, 256, 0, stream>>>(X, Xhp);

        dim3 grid((M / BM) * (O / BN));
        gemm_q4<<<grid, 512, 0, stream>>>(Xhp, Wd, Bi, C, M, O, K);
    } else {
        dim3 grid((M / 128) * (O / 128));
        q4_gemm_fused<<<grid, 256, 0, stream>>>(X, WP, S, Z, Bi, C, M, O, K, NG);
    }
}

// Round 8
// 315.295 us; speedup vs baseline: 1.0136x; 1.0136x over previous
//
#include <hip/hip_runtime.h>

typedef __attribute__((ext_vector_type(8))) short short8;
typedef __attribute__((ext_vector_type(4))) float f32x4;
typedef unsigned short u16;
typedef unsigned int u32;

#define BM 256
#define BN 256
#define BK 32
#define NBUF 4
#define LDP 40   // fused-fallback padded stride

__device__ __forceinline__ u16 f2bf_rne(float f) {
    u32 u = __float_as_uint(f);
    return (u16)((u + 0x7fffu + ((u >> 16) & 1u)) >> 16);
}
__device__ __forceinline__ float bf2f(u16 b) { return __uint_as_float(((u32)b) << 16); }

// ---------------- prep kernels (unchanged, proven) ----------------

__global__ __launch_bounds__(256)
void prep_w(const int* __restrict__ WP, const float* __restrict__ S,
            const float* __restrict__ Z, u16* __restrict__ Wd, int NG)
{
    const int tid = blockIdx.x * blockDim.x + threadIdx.x;
    const int o = tid / NG, g = tid % NG;
    const float s = S[o * NG + g];
    const float nzs = -Z[o * NG + g] * s;
    const int4* p = (const int4*)&WP[(size_t)(o * NG + g) * 16];
    __align__(16) u16 out[32];
    #pragma unroll
    for (int q4 = 0; q4 < 4; ++q4) {
        const int4 v4 = p[q4];
        const int vv[4] = {v4.x, v4.y, v4.z, v4.w};
        #pragma unroll
        for (int j = 0; j < 4; ++j) {
            const int v = vv[j];
            out[(q4 * 4 + j) * 2]     = f2bf_rne(fmaf((float)(v & 15), s, nzs));
            out[(q4 * 4 + j) * 2 + 1] = f2bf_rne(fmaf((float)((v >> 4) & 15), s, nzs));
        }
    }
    uint4* dst = (uint4*)&Wd[(size_t)tid * 32];
    const uint4* src = (const uint4*)out;
    dst[0] = src[0]; dst[1] = src[1]; dst[2] = src[2]; dst[3] = src[3];
}

__global__ __launch_bounds__(256)
void prep_x(const float* __restrict__ X, u16* __restrict__ Xh)
{
    const int tid = blockIdx.x * blockDim.x + threadIdx.x;
    const float4 v0 = ((const float4*)X)[tid * 2];
    const float4 v1 = ((const float4*)X)[tid * 2 + 1];
    const float f[8] = {v0.x, v0.y, v0.z, v0.w, v1.x, v1.y, v1.z, v1.w};
    __align__(16) u16 h[8];
    #pragma unroll
    for (int j = 0; j < 8; ++j) h[j] = f2bf_rne(f[j]);
    ((uint4*)Xh)[tid] = *(uint4*)h;
}

// ------- deep-pipelined 256x256 GEMM: C = Xh·Wd^T + bias -------
// 512 thr (8 waves: 2m x 4n), BK=32, 4-deep LDS ring, counted vmcnt(8),
// ONE barrier per K-step, MFMA gated only by compiler's per-use lgkmcnt,
// conflict-free swizzle: phys_slot = (chunk + ((row>>1)&3)) & 3.

#define GLDS(gptr, ldsbase)                                                         \
    __builtin_amdgcn_global_load_lds(                                               \
        (const __attribute__((address_space(1))) u32*)(gptr),                       \
        (__attribute__((address_space(3))) u32*)(ldsbase), 16, 0, 0)

__global__ __launch_bounds__(512, 2)
void gemm_q4(const u16* __restrict__ Xh, const u16* __restrict__ Wd,
             const float* __restrict__ Bi, float* __restrict__ C,
             int M, int N, int K)
{
    // 4 ring buffers x 16KB per operand = 128 KiB total
    __shared__ __align__(16) u16 sA[NBUF * 8192];
    __shared__ __align__(16) u16 sB[NBUF * 8192];

    const int nbx = N / BN;                  // 16
    const int nwg = gridDim.x;               // 256 (%8==0 -> simple bijective)
    const int cpx = nwg >> 3;
    const int bid = blockIdx.x;
    const int swz = (bid & 7) * cpx + (bid >> 3);
    const int bx = swz % nbx, by = swz / nbx;
    const int brow = by * BM, bcol = bx * BN;

    const int t = threadIdx.x;
    const int lane = t & 63;
    const int wid = t >> 6;                  // 0..7
    const int wr = wid >> 2;                 // 0..1  (128-row block)
    const int wcn = wid & 3;                 // 0..3  (64-col block)
    const int fr = lane & 15;
    const int kslot = lane >> 4;             // logical chunk 0..3
    // read-side phys slot: (chunk + ((row>>1)&3)) & 3; frag base rows are
    // multiples of 16 so (row>>1)&3 == (fr>>1)&3.  Bank-quad per 16 fr-lanes:
    // (4*fr + slot)&7 sweeps {0,4,1,5,2,6,3,7} -> 2 lanes/quad = conflict-free.
    const int ps8 = (((kslot + ((fr >> 1) & 3)) & 3) << 3);   // u16 units

    // write side (DMA is linear): thread t covers row = t>>2, phys slot = t&3
    //  -> logical chunk = ((t&3) - ((row>>1)&3)) & 3, row>>1&3 = (lane>>3)&3
    const int srow = wid * 16 + (lane >> 2);
    const int schunk = (((lane & 3) - ((lane >> 3) & 3)) & 3) * 8;  // elem offset
    const u16* srcA0 = Xh + (size_t)(brow + srow) * K + schunk;
    const u16* srcA1 = Xh + (size_t)(brow + 128 + srow) * K + schunk;
    const u16* srcB0 = Wd + (size_t)(bcol + srow) * K + schunk;
    const u16* srcB1 = Wd + (size_t)(bcol + 128 + srow) * K + schunk;

    f32x4 acc[8][4];
    #pragma unroll
    for (int m = 0; m < 8; ++m)
        #pragma unroll
        for (int n = 0; n < 4; ++n) acc[m][n] = (f32x4)0.f;

    const int nkt = K / BK;                  // 128

#define STAGE(bufi, kt)                                                   \
    do {                                                                  \
        const size_t ko = (size_t)(kt) * BK;                              \
        char* baA = (char*)sA + (bufi) * 16384 + wid * 1024;              \
        char* baB = (char*)sB + (bufi) * 16384 + wid * 1024;              \
        GLDS(srcA0 + ko, baA);                                            \
        GLDS(srcA1 + ko, baA + 8192);                                     \
        GLDS(srcB0 + ko, baB);                                            \
        GLDS(srcB1 + ko, baB + 8192);                                     \
    } while (0)

    // ---- prologue: fill the 4-deep ring; tile 0 landed before loop ----
    STAGE(0, 0);
    STAGE(1, 1);
    STAGE(2, 2);
    STAGE(3, 3);
    asm volatile("s_waitcnt vmcnt(12)" ::: "memory");   // tile 0 landed
    asm volatile("s_barrier" ::: "memory");

    for (int kt = 0; kt < nkt; ++kt) {
        const int cur = kt & 3;
        const u16* bufA = sA + cur * 8192;
        const u16* bufB = sB + cur * 8192;

        // ---- fragment reads; MFMA gated per-use by compiler lgkmcnt ----
        short8 a[8], b[4];
        #pragma unroll
        for (int n = 0; n < 4; ++n) {
            const int row = wcn * 64 + n * 16 + fr;
            b[n] = *(const short8*)&bufB[row * 32 + ps8];
        }
        #pragma unroll
        for (int m = 0; m < 8; ++m) {
            const int row = wr * 128 + m * 16 + fr;
            a[m] = *(const short8*)&bufA[row * 32 + ps8];
        }

        __builtin_amdgcn_s_setprio(1);
        #pragma unroll
        for (int m = 0; m < 8; ++m)
            #pragma unroll
            for (int n = 0; n < 4; ++n)
                acc[m][n] = __builtin_amdgcn_mfma_f32_16x16x32_bf16(a[m], b[n], acc[m][n], 0, 0, 0);
        __builtin_amdgcn_s_setprio(0);

        // counted vmcnt: ensure tile kt+1 landed before next iter's reads.
        // outstanding here: 12 (3 staged tiles) steady-state -> oldest 4 = kt+1
        if (kt + 3 < nkt)      asm volatile("s_waitcnt vmcnt(8)" ::: "memory");
        else if (kt + 2 < nkt) asm volatile("s_waitcnt vmcnt(4)" ::: "memory");
        else                   asm volatile("s_waitcnt vmcnt(0)" ::: "memory");
        asm volatile("s_barrier" ::: "memory");
        // all waves' reads of buf[cur] retired (reads precede own barrier
        // arrival) -> safe to restage it; lands gated by later vmcnt+barrier
        if (kt + 4 < nkt) STAGE(cur, kt + 4);
    }

    // ---- epilogue: C = acc + bias (layout: col=lane&15, row=(lane>>4)*4+i) ----
    const int row4 = (lane >> 4) << 2;
    const int col = lane & 15;
    #pragma unroll
    for (int n = 0; n < 4; ++n) {
        const int gc = bcol + wcn * 64 + n * 16 + col;
        const float bb = Bi[gc];
        #pragma unroll
        for (int m = 0; m < 8; ++m) {
            const int gr = brow + wr * 128 + m * 16 + row4;
            #pragma unroll
            for (int i = 0; i < 4; ++i)
                C[(size_t)(gr + i) * N + gc] = acc[m][n][i] + bb;
        }
    }
}
#undef STAGE
#undef GLDS

// ---------------- fused fallback (round-1 kernel, proven) ----------------

__global__ __launch_bounds__(256, 2)
void q4_gemm_fused(const float* __restrict__ X, const int* __restrict__ WP,
                   const float* __restrict__ S, const float* __restrict__ Z,
                   const float* __restrict__ Bi, float* __restrict__ C,
                   int M, int N, int K, int NG)
{
    __shared__ __align__(16) u16 sa_hi[128][LDP];
    __shared__ __align__(16) u16 sa_lo[128][LDP];
    __shared__ __align__(16) u16 sb_hi[128][LDP];
    __shared__ __align__(16) u16 sb_lo[128][LDP];

    const int nbx = N / 128;
    const int bx = blockIdx.x % nbx;
    const int by = blockIdx.x / nbx;
    const int brow = by * 128, bcol = bx * 128;

    const int t = threadIdx.x;
    const int lane = t & 63;
    const int wid = t >> 6;
    const int wr = wid >> 1, wc = wid & 1;
    const int xc4 = t & 7, xr0 = t >> 3;
    const int wrow = t >> 1, whalf = t & 1;
    const int Kh = K >> 1;

    f32x4 acc[4][4];
    #pragma unroll
    for (int m = 0; m < 4; ++m)
        #pragma unroll
        for (int n = 0; n < 4; ++n) acc[m][n] = (f32x4)0.f;

    const int fr = lane & 15;
    const int k8 = (lane >> 4) << 3;

    const int nkt = K / 32;
    for (int kt = 0; kt < nkt; ++kt) {
        #pragma unroll
        for (int p = 0; p < 4; ++p) {
            const int r = xr0 + p * 32;
            const float4 v = *(const float4*)&X[(size_t)(brow + r) * K + kt * 32 + xc4 * 4];
            u16 h[4], l[4];
            const float f[4] = {v.x, v.y, v.z, v.w};
            #pragma unroll
            for (int j = 0; j < 4; ++j) {
                h[j] = f2bf_rne(f[j]);
                l[j] = f2bf_rne(f[j] - bf2f(h[j]));
            }
            *(ushort4*)&sa_hi[r][xc4 * 4] = *(ushort4*)h;
            *(ushort4*)&sa_lo[r][xc4 * 4] = *(ushort4*)l;
        }
        {
            const int n = bcol + wrow;
            const float s = S[n * NG + kt];
            const float z = Z[n * NG + kt];
            const float nzs = -z * s;
            const int4* pp = (const int4*)&WP[(size_t)n * Kh + kt * 16 + whalf * 8];
            const int4 p0 = pp[0], p1 = pp[1];
            const int vals[8] = {p0.x, p0.y, p0.z, p0.w, p1.x, p1.y, p1.z, p1.w};
            __align__(16) u16 hi[16], lo[16];
            #pragma unroll
            for (int j = 0; j < 8; ++j) {
                const int v = vals[j];
                const float w0 = fmaf((float)(v & 15), s, nzs);
                const float w1 = fmaf((float)((v >> 4) & 15), s, nzs);
                hi[2 * j] = f2bf_rne(w0); lo[2 * j] = f2bf_rne(w0 - bf2f(hi[2 * j]));
                hi[2 * j + 1] = f2bf_rne(w1); lo[2 * j + 1] = f2bf_rne(w1 - bf2f(hi[2 * j + 1]));
            }
            #pragma unroll
            for (int q = 0; q < 4; ++q) {
                *(ushort4*)&sb_hi[wrow][whalf * 16 + q * 4] = *(ushort4*)&hi[q * 4];
                *(ushort4*)&sb_lo[wrow][whalf * 16 + q * 4] = *(ushort4*)&lo[q * 4];
            }
        }
        __syncthreads();

        short8 ah[4], al[4], bh[4], bl[4];
        #pragma unroll
        for (int m = 0; m < 4; ++m) {
            ah[m] = *(const short8*)&sa_hi[wr * 64 + m * 16 + fr][k8];
            al[m] = *(const short8*)&sa_lo[wr * 64 + m * 16 + fr][k8];
        }
        #pragma unroll
        for (int n = 0; n < 4; ++n) {
            bh[n] = *(const short8*)&sb_hi[wc * 64 + n * 16 + fr][k8];
            bl[n] = *(const short8*)&sb_lo[wc * 64 + n * 16 + fr][k8];
        }
        #pragma unroll
        for (int m = 0; m < 4; ++m)
            #pragma unroll
            for (int n = 0; n < 4; ++n) {
                acc[m][n] = __builtin_amdgcn_mfma_f32_16x16x32_bf16(ah[m], bh[n], acc[m][n], 0, 0, 0);
                acc[m][n] = __builtin_amdgcn_mfma_f32_16x16x32_bf16(ah[m], bl[n], acc[m][n], 0, 0, 0);
                acc[m][n] = __builtin_amdgcn_mfma_f32_16x16x32_bf16(al[m], bh[n], acc[m][n], 0, 0, 0);
            }
        __syncthreads();
    }

    const int row4 = (lane >> 4) << 2;
    const int col = lane & 15;
    #pragma unroll
    for (int n = 0; n < 4; ++n) {
        const int gc = bcol + wc * 64 + n * 16 + col;
        const float bb = Bi[gc];
        #pragma unroll
        for (int m = 0; m < 4; ++m) {
            const int gr = brow + wr * 64 + m * 16 + row4;
            #pragma unroll
            for (int i = 0; i < 4; ++i)
                C[(size_t)(gr + i) * N + gc] = acc[m][n][i] + bb;
        }
    }
}

// ---------------- launch ----------------

extern "C" void kernel_launch(void* const* d_in, const int* in_sizes, int n_in,
                              void* d_out, int out_size, void* d_ws, size_t ws_size,
                              hipStream_t stream)
{
    const float* X  = (const float*)d_in[0];
    const int*   WP = (const int*)d_in[1];
    const float* S  = (const float*)d_in[2];
    const float* Z  = (const float*)d_in[3];
    const float* Bi = (const float*)d_in[4];
    float* C = (float*)d_out;

    const int O  = in_sizes[4];            // 4096
    const int NG = in_sizes[2] / O;        // 128
    const int K  = NG * 32;                // 4096
    const int M  = in_sizes[0] / K;        // 4096

    const size_t needW = (size_t)O * K * 2;
    const size_t needX = (size_t)M * K * 2;
    const size_t need = needW + needX;

    if (ws_size >= need && (M % BM) == 0 && (O % BN) == 0) {
        u16* Wd  = (u16*)d_ws;
        u16* Xhp = Wd + (size_t)O * K;

        prep_w<<<(O * NG) / 256, 256, 0, stream>>>(WP, S, Z, Wd, NG);
        prep_x<<<(M * K / 8) / 256, 256, 0, stream>>>(X, Xhp);

        dim3 grid((M / BM) * (O / BN));
        gemm_q4<<<grid, 512, 0, stream>>>(Xhp, Wd, Bi, C, M, O, K);
    } else {
        dim3 grid((M / 128) * (O / 128));
        q4_gemm_fused<<<grid, 256, 0, stream>>>(X, WP, S, Z, Bi, C, M, O, K, NG);
    }
}